// Round 11
// baseline (30.533 us; speedup 1.0000x reference)
//
#include <hip/hip_runtime.h>
#include <math.h>

// PoolingConnection fused: out[k,i,j] = max(s[k, 6i:6i+64, 6j:6j+64]) clipped at 384.
// F=128, H=W=384, stride=6, window=64, out=[128,64,64].
//
// H = 64 segments of exactly 6 rows. out[i] = max(segm[i..i+9], segp[i+10])
// (segments > 63 -> -inf). segm[g] = 2D max of rows 6g..6g+5 (W-pooled),
// segp[g] = rows 6g..6g+3 only. Per segment (one wave): lane l owns cols
// 6l..6l+5 (3x float2), vertical 6-row max in registers, then the proven
// shuffle sliding-window (lanes j..j+9 full + first-4-cols of lane j+10).
//
// ZERO-HALO + 256 BLOCKS: block=(k,half); half0 owns segs 0..31, half1 owns
// segs 32..63 (every input byte read exactly once, 2 segs/wave). half1
// publishes segm[32..40]+segp[32..41] (19x64 floats) to global ws right after
// phase 1 (release flag), then finishes rows 32..63 locally -- NEVER waits.
// half0 finishes rows 0..21 locally, then ONE thread acquires the flag
// (round-8 failure was 1024 spinners/block saturating the coherence fabric),
// imports, and finishes rows 22..31. Deadlock-free: 256 blocks <= 256 CUs all
// co-resident; producer is wait-free. Replay-safe: stale SENT flag short-
// circuits to value-identical deterministic data; 0xAA poison != SENT forces
// a real wait on the first timed pass.

constexpr int F  = 128;
constexpr int H  = 384;
constexpr int W  = 384;
constexpr int ST = 6;
constexpr int OH = 64;
constexpr int OW = 64;

constexpr unsigned int SENT = 0x13572468u;

#define NINF (-__builtin_huge_valf())

// shuffle value from lane (lane+d); lanes beyond 63 contribute -inf
// (implements the right-edge window clipping for free).
__device__ __forceinline__ float sh_ninf(float v, int lane, int d) {
    float r = __shfl(v, lane + d, 64);
    return (lane + d > 63) ? NINF : r;
}

// sliding max over lanes [l..l+9] of m, plus first-4-cols of lane l+10
__device__ __forceinline__ float slide_window(float m, float p3, int lane) {
    const float a1 = fmaxf(m,  sh_ninf(m,  lane, 1));   // [l, l+1]
    const float a2 = fmaxf(a1, sh_ninf(a1, lane, 2));   // [l .. l+3]
    const float a3 = fmaxf(a2, sh_ninf(a2, lane, 4));   // [l .. l+7]
    const float a4 = fmaxf(a3, sh_ninf(a1, lane, 8));   // [l .. l+9]
    return fmaxf(a4, sh_ninf(p3, lane, 10));            // + 4 cols of l+10
}

// Local LDS seg index: half0 -> local == global (0..31), imports at 32..41.
// half1 -> local = global - 32 (0..31), -inf clip pad at 32..41.
__global__ __launch_bounds__(1024) void pool_fused_kernel(const float* __restrict__ s,
                                                          float* __restrict__ out,
                                                          float* __restrict__ wsd,
                                                          unsigned int* __restrict__ wsf) {
    __shared__ float segm[42][64];   // 10.5 KiB
    __shared__ float segp[42][64];   // 10.5 KiB

    const int k    = blockIdx.x >> 1;
    const int half = blockIdx.x & 1;
    const int sbeg = half ? 32 : 0;   // first owned global segment

    const int tid  = threadIdx.x;
    const int wv   = tid >> 6;        // 0..15
    const int lane = tid & 63;

    // half1: -inf pad for local segs 32..41 (= global 64..73, bottom clipping)
    if (half) {
        for (int job = tid; job < 10 * 64; job += 1024) {
            const int g = 32 + (job >> 6);
            const int j = job & 63;
            segm[g][j] = NINF;
            segp[g][j] = NINF;
        }
    }

    // ---- Phase 1: exactly 2 owned segments per wave ----
    const float* base = s + ((size_t)k * H + sbeg * ST) * W + lane * 6;
    #pragma unroll
    for (int it = 0; it < 2; ++it) {
        const int sl = wv + it * 16;             // local seg index 0..31
        const float* seg = base + (size_t)sl * ST * W;
        float vm6 = NINF, vp6 = NINF;            // rows 0..5: all-6 / first-4 cols
        float vm4 = NINF, vp4 = NINF;            // rows 0..3 only
        #pragma unroll
        for (int t = 0; t < 6; ++t) {
            const float* row = seg + (size_t)t * W;
            const float2 e0 = *reinterpret_cast<const float2*>(row);
            const float2 e1 = *reinterpret_cast<const float2*>(row + 2);
            const float2 e2 = *reinterpret_cast<const float2*>(row + 4);
            const float p3 = fmaxf(fmaxf(e0.x, e0.y), fmaxf(e1.x, e1.y));
            const float m  = fmaxf(p3, fmaxf(e2.x, e2.y));
            vm6 = fmaxf(vm6, m);
            vp6 = fmaxf(vp6, p3);
            if (t < 4) { vm4 = fmaxf(vm4, m); vp4 = fmaxf(vp4, p3); }
        }
        segm[sl][lane] = slide_window(vm6, vp6, lane);
        segp[sl][lane] = slide_window(vm4, vp4, lane);
    }
    __syncthreads();

    if (half) {
        // ---- Publish boundary data: segm local 0..8 (= global 32..40),
        //      segp local 0..9 (= global 32..41). 19x64 floats. ----
        if (tid < 19 * 64) {
            const int g = tid >> 6, j = tid & 63;
            wsd[(size_t)k * 1216 + tid] = (g < 9) ? segm[g][j] : segp[g - 9][j];
        }
        __syncthreads();
        if (tid == 0) {
            __threadfence();   // agent-scope: data visible before flag
            __hip_atomic_store(&wsf[k], SENT, __ATOMIC_RELEASE,
                               __HIP_MEMORY_SCOPE_AGENT);
        }
        // ---- Phase 2: out rows 32..63 (all local; pad handles clipping) ----
        for (int job = tid; job < 32 * 64; job += 1024) {
            const int li = job >> 6;             // local 0..31 -> global 32+li
            const int j  = job & 63;
            float acc = segp[li + 10][j];
            #pragma unroll
            for (int t = 0; t < 10; ++t) acc = fmaxf(acc, segm[li + t][j]);
            out[((size_t)k * OH + 32 + li) * OW + j] = acc;
        }
    } else {
        // ---- Phase 2A: out rows 0..21 (fully local) ----
        for (int job = tid; job < 22 * 64; job += 1024) {
            const int li = job >> 6;
            const int j  = job & 63;
            float acc = segp[li + 10][j];
            #pragma unroll
            for (int t = 0; t < 10; ++t) acc = fmaxf(acc, segm[li + t][j]);
            out[((size_t)k * OH + li) * OW + j] = acc;
        }
        // ---- Import half1's boundary data (single-thread acquire spin) ----
        if (tid == 0) {
            while (__hip_atomic_load(&wsf[k], __ATOMIC_ACQUIRE,
                                     __HIP_MEMORY_SCOPE_AGENT) != SENT) {
                __builtin_amdgcn_s_sleep(8);
            }
        }
        __syncthreads();
        if (tid < 19 * 64) {
            const int g = tid >> 6, j = tid & 63;
            const float v = wsd[(size_t)k * 1216 + tid];
            if (g < 9) segm[32 + g][j] = v;      // global segs 32..40
            else       segp[32 + (g - 9)][j] = v; // global segs 32..41
        }
        __syncthreads();
        // ---- Phase 2B: out rows 22..31 ----
        for (int job = tid; job < 10 * 64; job += 1024) {
            const int li = 22 + (job >> 6);      // 22..31
            const int j  = job & 63;
            float acc = segp[li + 10][j];        // imported 32..41
            #pragma unroll
            for (int t = 0; t < 10; ++t) acc = fmaxf(acc, segm[li + t][j]); // 22..40
            out[((size_t)k * OH + li) * OW + j] = acc;
        }
    }
}

extern "C" void kernel_launch(void* const* d_in, const int* in_sizes, int n_in,
                              void* d_out, int out_size, void* d_ws, size_t ws_size,
                              hipStream_t stream) {
    const float* s = (const float*)d_in[0];
    float* out     = (float*)d_out;
    float* wsd        = (float*)d_ws;                        // [128][1216] floats
    unsigned int* wsf = (unsigned int*)(wsd + (size_t)F * 1216);  // [128] flags

    pool_fused_kernel<<<F * 2, 1024, 0, stream>>>(s, out, wsd, wsf);
}

// Round 12
// 17.972 us; speedup vs baseline: 1.6989x; 1.6989x over previous
//
#include <hip/hip_runtime.h>
#include <math.h>

// PoolingConnection fused: out[k,i,j] = max(s[k, 6i:6i+64, 6j:6j+64]) clipped at 384.
// F=128, H=W=384, stride=6, window=64, out=[128,64,64].
//
// H = 64 segments of exactly 6 rows. out[i] = max(segm[i..i+9], segp[i+10])
// (segments > 63 -> -inf). segm[g] = 2D max of rows 6g..6g+5 (W-pooled),
// segp[g] = rows 6g..6g+3 only. Per segment (one wave): lane l owns cols
// 6l..6l+5 (3x float2), vertical 6-row max in registers, then the proven
// shuffle sliding-window (lanes j..j+9 full + first-4-cols of lane j+10).
//
// ZERO-HALO, ZERO-SYNC tiling: one block per FEATURE. 128 blocks x 1024
// threads; 64 segments / 16 waves = exactly 4 per wave; every input byte is
// read exactly once (75.5 MB, the information-theoretic minimum); all 64
// output rows are block-local so no cross-block exchange at all.
//
// Final form (session best, round 9 = 17.8 us): sits at the measured
// 128-CU read ceiling (~4.8 TB/s) + ~2 us launch. Measured-worse configs:
// halo+256blk 18.5 (R4), two-kernel 19.4 (R5), float4+LDS-regroup 19.2 (R7),
// nontemporal 26.9 (R10), cross-block exchange 30.5/45.4 (R11/R8 — also a
// cross-XCD L2 coherence hazard, absmax 7.8e-3).

constexpr int F  = 128;
constexpr int H  = 384;
constexpr int W  = 384;
constexpr int ST = 6;
constexpr int OH = 64;
constexpr int OW = 64;

constexpr int NSEG   = 64;        // segments per feature (all of H)
constexpr int SEGPAD = NSEG + 10; // -inf padded for fixed 10-tap combine

#define NINF (-__builtin_huge_valf())

// shuffle value from lane (lane+d); lanes beyond 63 contribute -inf
// (implements the right-edge window clipping for free).
__device__ __forceinline__ float sh_ninf(float v, int lane, int d) {
    float r = __shfl(v, lane + d, 64);
    return (lane + d > 63) ? NINF : r;
}

// sliding max over lanes [l..l+9] of m, plus first-4-cols of lane l+10
__device__ __forceinline__ float slide_window(float m, float p3, int lane) {
    const float a1 = fmaxf(m,  sh_ninf(m,  lane, 1));   // [l, l+1]
    const float a2 = fmaxf(a1, sh_ninf(a1, lane, 2));   // [l .. l+3]
    const float a3 = fmaxf(a2, sh_ninf(a2, lane, 4));   // [l .. l+7]
    const float a4 = fmaxf(a3, sh_ninf(a1, lane, 8));   // [l .. l+9]
    return fmaxf(a4, sh_ninf(p3, lane, 10));            // + 4 cols of l+10
}

__global__ __launch_bounds__(1024) void pool_fused_kernel(const float* __restrict__ s,
                                                          float* __restrict__ out) {
    __shared__ float segm[SEGPAD][64];   // 18.5 KiB
    __shared__ float segp[SEGPAD][64];   // 18.5 KiB

    const int k    = blockIdx.x;
    const int tid  = threadIdx.x;
    const int wv   = tid >> 6;        // 0..15
    const int lane = tid & 63;

    // -inf pad for segs 64..73 (bottom clipping for out i >= 54)
    for (int job = tid; job < 10 * 64; job += 1024) {
        const int g = NSEG + (job >> 6);
        const int j = job & 63;
        segm[g][j] = NINF;
        segp[g][j] = NINF;
    }

    // ---- Phase 1: exactly 4 segments per wave (gl = wv + 16*it) ----
    const float* base = s + (size_t)k * H * W + lane * 6;
    #pragma unroll
    for (int it = 0; it < 4; ++it) {
        const int gl = wv + it * 16;
        const float* seg = base + (size_t)gl * ST * W;
        float vm6 = NINF, vp6 = NINF;    // rows 0..5: all-6-cols / first-4-cols
        float vm4 = NINF, vp4 = NINF;    // rows 0..3 only
        #pragma unroll
        for (int t = 0; t < 6; ++t) {
            const float* row = seg + (size_t)t * W;
            const float2 e0 = *reinterpret_cast<const float2*>(row);
            const float2 e1 = *reinterpret_cast<const float2*>(row + 2);
            const float2 e2 = *reinterpret_cast<const float2*>(row + 4);
            const float p3 = fmaxf(fmaxf(e0.x, e0.y), fmaxf(e1.x, e1.y));
            const float m  = fmaxf(p3, fmaxf(e2.x, e2.y));
            vm6 = fmaxf(vm6, m);
            vp6 = fmaxf(vp6, p3);
            if (t < 4) { vm4 = fmaxf(vm4, m); vp4 = fmaxf(vp4, p3); }
        }
        segm[gl][lane] = slide_window(vm6, vp6, lane);
        segp[gl][lane] = slide_window(vm4, vp4, lane);
    }
    __syncthreads();

    // ---- Phase 2: out[li] = max(segm[li..li+9], segp[li+10]) ----
    for (int job = tid; job < 64 * 64; job += 1024) {
        const int li = job >> 6;
        const int j  = job & 63;
        float acc = segp[li + 10][j];
        #pragma unroll
        for (int t = 0; t < 10; ++t) acc = fmaxf(acc, segm[li + t][j]);
        out[((size_t)k * OH + li) * OW + j] = acc;   // coalesced
    }
}

extern "C" void kernel_launch(void* const* d_in, const int* in_sizes, int n_in,
                              void* d_out, int out_size, void* d_ws, size_t ws_size,
                              hipStream_t stream) {
    const float* s = (const float*)d_in[0];
    float* out     = (float*)d_out;
    pool_fused_kernel<<<F, 1024, 0, stream>>>(s, out);
}